// Round 9
// baseline (369.772 us; speedup 1.0000x reference)
//
#include <hip/hip_runtime.h>
#include <hip/hip_bf16.h>
#include <stdint.h>

typedef unsigned short u16;
typedef unsigned int   u32;
typedef short bf16x8 __attribute__((ext_vector_type(8)));
typedef float f32x4  __attribute__((ext_vector_type(4)));

// may_alias views for type-punned LDS/global accesses (TBAA-safe)
typedef bf16x8 __attribute__((__may_alias__)) bf16x8_a;
typedef uint4  __attribute__((__may_alias__)) uint4_a;
typedef uint2  __attribute__((__may_alias__)) uint2_a;
typedef float4 __attribute__((__may_alias__)) float4_a;

#define MFMA_BF16(a,b,c) __builtin_amdgcn_mfma_f32_16x16x32_bf16((a),(b),(c),0,0,0)
#define L2E 1.44269504088896340736f

// B=4, S=2048, D=1024, H=16, DH=64
#define SEQ 2048
#define DMODEL 1024
#define NH 16
#define DH 64

__device__ __forceinline__ u16 f2bf(float f) {
  u32 u = __builtin_bit_cast(u32, f);
  u += 0x7FFFu + ((u >> 16) & 1u);
  return (u16)(u >> 16);
}

__device__ __forceinline__ u32 pack_bf2(float a, float b) {
  return ((u32)f2bf(a)) | (((u32)f2bf(b)) << 16);
}

// ---------------------------------------------------------------------------
// QKV projection from f32 inputs: y[m,n] = sum_k x[m,k]*W[n,k] + bias[n].
// 128x128 tile, BK=32, MFMA 16x16x32 bf16 (f32 accumulate).
// Q/K/V stored bf16 in ws as [B,H,S,DH]; Q pre-scaled 0.125 (=1/sqrt(DH)).
// ---------------------------------------------------------------------------
__global__ __launch_bounds__(256, 2) void qkv_gemm(
    const float* __restrict__ X,
    const float* __restrict__ Wq, const float* __restrict__ Wk, const float* __restrict__ Wv,
    const float* __restrict__ Bq, const float* __restrict__ Bk, const float* __restrict__ Bv,
    u16* __restrict__ Qo, u16* __restrict__ Ko, u16* __restrict__ Vo)
{
  __shared__ u16 As[128 * 32];   // [m][k] bf16
  __shared__ u16 Bs[128 * 32];   // [n][k] bf16

  const int tid  = threadIdx.x;
  const int lane = tid & 63;
  const int wid  = tid >> 6;
  const int l16  = lane & 15;
  const int quad = lane >> 4;
  const int wm   = (wid >> 1) * 64;
  const int wn   = (wid & 1) * 64;

  const int m0 = blockIdx.x * 128;
  const int n0 = blockIdx.y * 128;
  const int pj = blockIdx.z;

  const float* W    = (pj == 0) ? Wq : (pj == 1) ? Wk : Wv;
  const float* Bias = (pj == 0) ? Bq : (pj == 1) ? Bk : Bv;
  u16*         Out  = (pj == 0) ? Qo : (pj == 1) ? Ko : Vo;
  const float scale = (pj == 0) ? 0.125f : 1.0f;

  f32x4 acc[4][4];
#pragma unroll
  for (int i = 0; i < 4; i++)
#pragma unroll
    for (int j = 0; j < 4; j++) acc[i][j] = (f32x4){0.f, 0.f, 0.f, 0.f};

  for (int kt = 0; kt < DMODEL; kt += 32) {
    __syncthreads();
#pragma unroll
    for (int i = 0; i < 4; i++) {
      const int ch = i * 256 + tid;        // 0..1023
      const int r = ch >> 3, c = ch & 7;   // row, float4-chunk (8 x 4 = 32/row)
      float4 xa = *(const float4_a*)(X + (size_t)(m0 + r) * DMODEL + kt + c * 4);
      float4 wa = *(const float4_a*)(W + (size_t)(n0 + r) * DMODEL + kt + c * 4);
      uint2 xp, wp;
      xp.x = pack_bf2(xa.x, xa.y);  xp.y = pack_bf2(xa.z, xa.w);
      wp.x = pack_bf2(wa.x, wa.y);  wp.y = pack_bf2(wa.z, wa.w);
      *(uint2_a*)&As[r * 32 + c * 4] = xp;
      *(uint2_a*)&Bs[r * 32 + c * 4] = wp;
    }
    __syncthreads();

    bf16x8 a[4], b[4];
#pragma unroll
    for (int mt = 0; mt < 4; mt++)
      a[mt] = *(const bf16x8_a*)&As[(wm + mt * 16 + l16) * 32 + quad * 8];
#pragma unroll
    for (int nt = 0; nt < 4; nt++)
      b[nt] = *(const bf16x8_a*)&Bs[(wn + nt * 16 + l16) * 32 + quad * 8];
#pragma unroll
    for (int mt = 0; mt < 4; mt++)
#pragma unroll
      for (int nt = 0; nt < 4; nt++)
        acc[mt][nt] = MFMA_BF16(a[mt], b[nt], acc[mt][nt]);
  }

  // Epilogue: C layout col = l16 (n), row = quad*4 + r (m). Write [B,H,S,DH].
#pragma unroll
  for (int mt = 0; mt < 4; mt++) {
#pragma unroll
    for (int nt = 0; nt < 4; nt++) {
      const int n = n0 + wn + nt * 16 + l16;
      const float bias = Bias[n];
      const int h = n >> 6, dh = n & 63;
#pragma unroll
      for (int r = 0; r < 4; r++) {
        const int m = m0 + wm + mt * 16 + quad * 4 + r;
        const int bb = m >> 11, ss = m & 2047;
        const float v = (acc[mt][nt][r] + bias) * scale;
        Out[((((size_t)bb * NH + h) * SEQ + ss) << 6) + dh] = f2bf(v);
      }
    }
  }
}

// ---------------------------------------------------------------------------
// Causal flash attention (r5 structure, certified by cross-orientation
// agreement + oracle). Q,K,V bf16 [B*H][S][DH], Q pre-scaled 1/8.
// OUTPUT IS FLOAT32 [B,S,D]  (the round-8 fix).
// ---------------------------------------------------------------------------
__global__ __launch_bounds__(256, 2) void flash_attn(
    const u16* __restrict__ Q, const u16* __restrict__ K, const u16* __restrict__ V,
    float* __restrict__ O)
{
  __shared__ u16 Ks[128 * 72];         // [kv][72]  (also stages the Q tile)
  __shared__ u16 VTs[64 * 136];        // [dh][136] = V^T
  __shared__ u16 Ps[4 * 32 * 136];     // per-wave [32 q][136]

  const int tid  = threadIdx.x;
  const int lane = tid & 63;
  const int wid  = tid >> 6;
  const int l16  = lane & 15;
  const int quad = lane >> 4;

  const int qt = blockIdx.x;             // 0..15
  const int bh = blockIdx.y;             // 0..63
  const int bb = bh >> 4, hh = bh & 15;
  const int qbase = qt * 128;

  const u16* Qh = Q + (size_t)bh * (SEQ * DH);
  const u16* Kh = K + (size_t)bh * (SEQ * DH);
  const u16* Vh = V + (size_t)bh * (SEQ * DH);

#pragma unroll
  for (int i = 0; i < 4; i++) {
    const int ch = i * 256 + tid;
    const int r = ch >> 3, c = ch & 7;
    *(uint4_a*)&Ks[r * 72 + c * 8] = *(const uint4_a*)(Qh + (size_t)(qbase + r) * DH + c * 8);
  }
  __syncthreads();

  bf16x8 qf[2][2];
#pragma unroll
  for (int qt2 = 0; qt2 < 2; qt2++)
#pragma unroll
    for (int ks = 0; ks < 2; ks++)
      qf[qt2][ks] = *(const bf16x8_a*)&Ks[(wid * 32 + qt2 * 16 + l16) * 72 + ks * 32 + quad * 8];

  f32x4 o[2][4];
#pragma unroll
  for (int qt2 = 0; qt2 < 2; qt2++)
#pragma unroll
    for (int dt = 0; dt < 4; dt++) o[qt2][dt] = (f32x4){0.f, 0.f, 0.f, 0.f};

  float mold[2][4], lsum[2][4];
#pragma unroll
  for (int qt2 = 0; qt2 < 2; qt2++)
#pragma unroll
    for (int r = 0; r < 4; r++) { mold[qt2][r] = -1e30f; lsum[qt2][r] = 0.f; }

  for (int j = 0; j <= qt; j++) {
    __syncthreads();
    const int kb = j * 128;

#pragma unroll
    for (int i = 0; i < 4; i++) {
      const int ch = i * 256 + tid;
      const int r = ch >> 3, c = ch & 7;
      *(uint4_a*)&Ks[r * 72 + c * 8] = *(const uint4_a*)(Kh + (size_t)(kb + r) * DH + c * 8);
    }
#pragma unroll
    for (int i = 0; i < 4; i++) {
      const int cv = i * 256 + tid;
      const int n = cv & 127, dc = cv >> 7;
      uint4 t = *(const uint4_a*)(Vh + (size_t)(kb + n) * DH + dc * 8);
      const u16* e = (const u16*)&t;
#pragma unroll
      for (int x = 0; x < 8; x++) VTs[(dc * 8 + x) * 136 + n] = e[x];
    }
    __syncthreads();

    f32x4 s[2][8];
#pragma unroll
    for (int rt = 0; rt < 8; rt++) {
      bf16x8 kf0 = *(const bf16x8_a*)&Ks[(rt * 16 + l16) * 72 + 0 + quad * 8];
      bf16x8 kf1 = *(const bf16x8_a*)&Ks[(rt * 16 + l16) * 72 + 32 + quad * 8];
#pragma unroll
      for (int qt2 = 0; qt2 < 2; qt2++) {
        f32x4 c = (f32x4){0.f, 0.f, 0.f, 0.f};
        c = MFMA_BF16(qf[qt2][0], kf0, c);
        c = MFMA_BF16(qf[qt2][1], kf1, c);
        s[qt2][rt] = c;
      }
    }

    if (j == qt) {
#pragma unroll
      for (int qt2 = 0; qt2 < 2; qt2++)
#pragma unroll
        for (int rt = 0; rt < 8; rt++) {
          const int kvl = rt * 16 + l16;
#pragma unroll
          for (int r = 0; r < 4; r++) {
            const int ql = wid * 32 + qt2 * 16 + quad * 4 + r;
            if (kvl > ql) s[qt2][rt][r] = -1e30f;
          }
        }
    }

#pragma unroll
    for (int qt2 = 0; qt2 < 2; qt2++) {
#pragma unroll
      for (int r = 0; r < 4; r++) {
        float mt = -1e30f;
#pragma unroll
        for (int rt = 0; rt < 8; rt++) mt = fmaxf(mt, s[qt2][rt][r]);
        mt = fmaxf(mt, __shfl_xor(mt, 1));
        mt = fmaxf(mt, __shfl_xor(mt, 2));
        mt = fmaxf(mt, __shfl_xor(mt, 4));
        mt = fmaxf(mt, __shfl_xor(mt, 8));
        const float mnew = fmaxf(mold[qt2][r], mt);
        const float a = __builtin_amdgcn_exp2f((mold[qt2][r] - mnew) * L2E);
        float ls = 0.f;
#pragma unroll
        for (int rt = 0; rt < 8; rt++) {
          const float p = __builtin_amdgcn_exp2f((s[qt2][rt][r] - mnew) * L2E);
          s[qt2][rt][r] = p;
          ls += p;
        }
        ls += __shfl_xor(ls, 1);
        ls += __shfl_xor(ls, 2);
        ls += __shfl_xor(ls, 4);
        ls += __shfl_xor(ls, 8);
        lsum[qt2][r] = lsum[qt2][r] * a + ls;
        mold[qt2][r] = mnew;
#pragma unroll
        for (int dt = 0; dt < 4; dt++) o[qt2][dt][r] *= a;
      }
    }

    u16* Pw = &Ps[wid * 32 * 136];
#pragma unroll
    for (int qt2 = 0; qt2 < 2; qt2++)
#pragma unroll
      for (int rt = 0; rt < 8; rt++)
#pragma unroll
        for (int r = 0; r < 4; r++)
          Pw[(qt2 * 16 + quad * 4 + r) * 136 + rt * 16 + l16] = f2bf(s[qt2][rt][r]);
    __syncthreads();

#pragma unroll
    for (int kb4 = 0; kb4 < 4; kb4++) {
      bf16x8 pa[2], vb[4];
#pragma unroll
      for (int qt2 = 0; qt2 < 2; qt2++)
        pa[qt2] = *(const bf16x8_a*)&Pw[(qt2 * 16 + l16) * 136 + kb4 * 32 + quad * 8];
#pragma unroll
      for (int dt = 0; dt < 4; dt++)
        vb[dt] = *(const bf16x8_a*)&VTs[(dt * 16 + l16) * 136 + kb4 * 32 + quad * 8];
#pragma unroll
      for (int qt2 = 0; qt2 < 2; qt2++)
#pragma unroll
        for (int dt = 0; dt < 4; dt++)
          o[qt2][dt] = MFMA_BF16(pa[qt2], vb[dt], o[qt2][dt]);
    }
  }

  // epilogue: FLOAT32 output [B,S,D]; C-layout row q = quad*4+r, col dh = dt*16+l16
#pragma unroll
  for (int qt2 = 0; qt2 < 2; qt2++) {
#pragma unroll
    for (int r = 0; r < 4; r++) {
      const float inv = 1.0f / lsum[qt2][r];
      const int qg = qbase + wid * 32 + qt2 * 16 + quad * 4 + r;
      float* orow = O + (size_t)((size_t)bb * SEQ + qg) * DMODEL + hh * 64;
#pragma unroll
      for (int dt = 0; dt < 4; dt++)
        orow[dt * 16 + l16] = o[qt2][dt][r] * inv;
    }
  }
}

// Distinctive-paint sentinel (host-decided, graph-safe)
__global__ void paintf(float* out, int n, float v) {
  int i = blockIdx.x * 256 + threadIdx.x;
  if (i < n) out[i] = v;
}

extern "C" void kernel_launch(void* const* d_in, const int* in_sizes, int n_in,
                              void* d_out, int out_size, void* d_ws, size_t ws_size,
                              hipStream_t stream) {
  float* out = (float*)d_out;   // reference output dtype = float32

  const size_t elems = (size_t)4 * SEQ * DMODEL;   // 8,388,608 per tensor
  if (ws_size < 3 * elems * sizeof(u16)) {          // 50.3 MB needed
    paintf<<<(out_size + 255) / 256, 256, 0, stream>>>(out, out_size, 3.0e38f);
    return;
  }

  const float* x  = (const float*)d_in[0];
  // d_in[1] = mask (causal, unused — structure is known)
  const float* Wq = (const float*)d_in[2];
  const float* bq = (const float*)d_in[3];
  const float* Wk = (const float*)d_in[4];
  const float* bk = (const float*)d_in[5];
  const float* Wv = (const float*)d_in[6];
  const float* bv = (const float*)d_in[7];

  u16* q = (u16*)d_ws;
  u16* k = q + elems;
  u16* v = k + elems;

  qkv_gemm<<<dim3(64, 8, 3), 256, 0, stream>>>(x, Wq, Wk, Wv, bq, bk, bv, q, k, v);
  flash_attn<<<dim3(16, 64), 256, 0, stream>>>(q, k, v, out);
}

// Round 10
// 312.998 us; speedup vs baseline: 1.1814x; 1.1814x over previous
//
#include <hip/hip_runtime.h>
#include <hip/hip_bf16.h>
#include <stdint.h>

typedef unsigned short u16;
typedef unsigned int   u32;
typedef short bf16x8 __attribute__((ext_vector_type(8)));
typedef float f32x4  __attribute__((ext_vector_type(4)));

// may_alias views for type-punned LDS/global accesses (TBAA-safe)
typedef bf16x8 __attribute__((__may_alias__)) bf16x8_a;
typedef uint4  __attribute__((__may_alias__)) uint4_a;
typedef uint2  __attribute__((__may_alias__)) uint2_a;
typedef float4 __attribute__((__may_alias__)) float4_a;

#define MFMA_BF16(a,b,c) __builtin_amdgcn_mfma_f32_16x16x32_bf16((a),(b),(c),0,0,0)
#define L2E 1.44269504088896340736f

// B=4, S=2048, D=1024, H=16, DH=64
#define SEQ 2048
#define DMODEL 1024
#define NH 16
#define DH 64

__device__ __forceinline__ u32 pack_bf2(float a, float b) {
  union { __hip_bfloat162 h; u32 u; } c;
  c.h = __float22bfloat162_rn(make_float2(a, b));   // v_cvt_pk path on gfx950
  return c.u;
}

__device__ __forceinline__ u16 f2bf(float f) {
  u32 u = __builtin_bit_cast(u32, f);
  u += 0x7FFFu + ((u >> 16) & 1u);
  return (u16)(u >> 16);
}

// ---------------------------------------------------------------------------
// QKV projection, f32 in -> bf16 ws. y = x @ W^T + b. 128x128 tile, BK=32,
// register-double-buffered staging (prefetch kt+32 drains during MFMA phase).
// Q: [B,H,S,DH] scaled 0.125. K: [B,H,S,DH]. V: TRANSPOSED [B,H,DH,S].
// ---------------------------------------------------------------------------
__global__ __launch_bounds__(256, 2) void qkv_gemm(
    const float* __restrict__ X,
    const float* __restrict__ Wq, const float* __restrict__ Wk, const float* __restrict__ Wv,
    const float* __restrict__ Bq, const float* __restrict__ Bk, const float* __restrict__ Bv,
    u16* __restrict__ Qo, u16* __restrict__ Ko, u16* __restrict__ Vo)
{
  __shared__ u16 As[128 * 32];   // [m][k] bf16
  __shared__ u16 Bs[128 * 32];   // [n][k] bf16

  const int tid  = threadIdx.x;
  const int lane = tid & 63;
  const int wid  = tid >> 6;
  const int l16  = lane & 15;
  const int quad = lane >> 4;
  const int wm   = (wid >> 1) * 64;
  const int wn   = (wid & 1) * 64;

  const int m0 = blockIdx.x * 128;
  const int n0 = blockIdx.y * 128;
  const int pj = blockIdx.z;

  const float* W    = (pj == 0) ? Wq : (pj == 1) ? Wk : Wv;
  const float* Bias = (pj == 0) ? Bq : (pj == 1) ? Bk : Bv;
  u16*         Out  = (pj == 0) ? Qo : (pj == 1) ? Ko : Vo;
  const float scale = (pj == 0) ? 0.125f : 1.0f;

  f32x4 acc[4][4];
#pragma unroll
  for (int i = 0; i < 4; i++)
#pragma unroll
    for (int j = 0; j < 4; j++) acc[i][j] = (f32x4){0.f, 0.f, 0.f, 0.f};

  // prefetch kt=0
  float4 gX[4], gW[4];
#pragma unroll
  for (int i = 0; i < 4; i++) {
    const int ch = i * 256 + tid;
    const int r = ch >> 3, c = ch & 7;
    gX[i] = *(const float4_a*)(X + (size_t)(m0 + r) * DMODEL + c * 4);
    gW[i] = *(const float4_a*)(W + (size_t)(n0 + r) * DMODEL + c * 4);
  }

  for (int kt = 0; kt < DMODEL; kt += 32) {
    __syncthreads();                       // prior frag reads done
#pragma unroll
    for (int i = 0; i < 4; i++) {
      const int ch = i * 256 + tid;
      const int r = ch >> 3, c = ch & 7;
      uint2 xp, wp;
      xp.x = pack_bf2(gX[i].x, gX[i].y);  xp.y = pack_bf2(gX[i].z, gX[i].w);
      wp.x = pack_bf2(gW[i].x, gW[i].y);  wp.y = pack_bf2(gW[i].z, gW[i].w);
      *(uint2_a*)&As[r * 32 + c * 4] = xp;
      *(uint2_a*)&Bs[r * 32 + c * 4] = wp;
    }
    __syncthreads();                       // staging visible (no vm outstanding)

    if (kt + 32 < DMODEL) {                // prefetch next; drains during MFMAs
#pragma unroll
      for (int i = 0; i < 4; i++) {
        const int ch = i * 256 + tid;
        const int r = ch >> 3, c = ch & 7;
        gX[i] = *(const float4_a*)(X + (size_t)(m0 + r) * DMODEL + kt + 32 + c * 4);
        gW[i] = *(const float4_a*)(W + (size_t)(n0 + r) * DMODEL + kt + 32 + c * 4);
      }
    }

    bf16x8 a[4], b[4];
#pragma unroll
    for (int mt = 0; mt < 4; mt++)
      a[mt] = *(const bf16x8_a*)&As[(wm + mt * 16 + l16) * 32 + quad * 8];
#pragma unroll
    for (int nt = 0; nt < 4; nt++)
      b[nt] = *(const bf16x8_a*)&Bs[(wn + nt * 16 + l16) * 32 + quad * 8];
#pragma unroll
    for (int mt = 0; mt < 4; mt++)
#pragma unroll
      for (int nt = 0; nt < 4; nt++)
        acc[mt][nt] = MFMA_BF16(a[mt], b[nt], acc[mt][nt]);
  }

  // Epilogue. C layout: col n = l16(+), row m = quad*4+r(+).
  if (pj == 2) {
    // V stored TRANSPOSED [B,H,DH,S]: per lane 4 consecutive s -> uint2 pack
#pragma unroll
    for (int mt = 0; mt < 4; mt++) {
#pragma unroll
      for (int nt = 0; nt < 4; nt++) {
        const int n = n0 + wn + nt * 16 + l16;
        const float bias = Bias[n];
        const int h = n >> 6, dh = n & 63;
        const int m = m0 + wm + mt * 16 + quad * 4;
        const int bb = m >> 11, ss = m & 2047;
        uint2 pk;
        pk.x = pack_bf2(acc[mt][nt][0] + bias, acc[mt][nt][1] + bias);
        pk.y = pack_bf2(acc[mt][nt][2] + bias, acc[mt][nt][3] + bias);
        *(uint2_a*)&Out[((size_t)(bb * NH + h) * DH + dh) * SEQ + ss] = pk;
      }
    }
  } else {
#pragma unroll
    for (int mt = 0; mt < 4; mt++) {
#pragma unroll
      for (int nt = 0; nt < 4; nt++) {
        const int n = n0 + wn + nt * 16 + l16;
        const float bias = Bias[n];
        const int h = n >> 6, dh = n & 63;
#pragma unroll
        for (int r = 0; r < 4; r++) {
          const int m = m0 + wm + mt * 16 + quad * 4 + r;
          const int bb = m >> 11, ss = m & 2047;
          Out[((((size_t)bb * NH + h) * SEQ + ss) << 6) + dh] = f2bf((acc[mt][nt][r] + bias) * scale);
        }
      }
    }
  }
}

// ---------------------------------------------------------------------------
// Causal flash attention, r4 orientation (S^T = K Q^T), f32 output.
// Q,K [B*H][S][DH]; V TRANSPOSED [B*H][DH][S]. Q pre-scaled 1/8.
// Per block 128 q (wave = 32 q as 2x16 cols). Register-dbuf K/V staging.
// P^T packed uint2 -> LDS -> B-operand. O^T in C-layout -> float4 stores.
// Long blocks (qt=15) dispatched first for causal tail balance.
// ---------------------------------------------------------------------------
__global__ __launch_bounds__(256, 2) void flash_attn(
    const u16* __restrict__ Q, const u16* __restrict__ K, const u16* __restrict__ VT,
    float* __restrict__ O)
{
  __shared__ u16 Ks[128 * 72];         // [kv][72]  (also stages Q)
  __shared__ u16 VTs[64 * 136];        // [dh][136]
  __shared__ u16 Ps[4 * 32 * 144];     // per-wave [32 q][144 kv]

  const int tid  = threadIdx.x;
  const int lane = tid & 63;
  const int wid  = tid >> 6;
  const int l16  = lane & 15;
  const int quad = lane >> 4;

  const int idx = blockIdx.x;            // 0..1023
  const int qt  = 15 - (idx >> 6);       // long blocks first
  const int bh  = idx & 63;
  const int bb = bh >> 4, hh = bh & 15;
  const int qbase = qt * 128;

  const u16* Qh = Q  + (size_t)bh * (SEQ * DH);
  const u16* Kh = K  + (size_t)bh * (SEQ * DH);
  const u16* Vh = VT + (size_t)bh * (DH * SEQ);

  // ---- stage Q via Ks, pull B-operand frags (B[n=q][k=dh]) ----
#pragma unroll
  for (int i = 0; i < 4; i++) {
    const int ch = i * 256 + tid;
    const int r = ch >> 3, c = ch & 7;
    *(uint4_a*)&Ks[r * 72 + c * 8] = *(const uint4_a*)(Qh + (size_t)(qbase + r) * DH + c * 8);
  }
  __syncthreads();

  bf16x8 qf[2][2];
#pragma unroll
  for (int ct = 0; ct < 2; ct++)
#pragma unroll
    for (int ks = 0; ks < 2; ks++)
      qf[ct][ks] = *(const bf16x8_a*)&Ks[(wid * 32 + ct * 16 + l16) * 72 + ks * 32 + quad * 8];

  f32x4 o[4][2];                         // O^T [dt][ct]: row dh=quad*4+r, col q=l16
#pragma unroll
  for (int dt = 0; dt < 4; dt++)
#pragma unroll
    for (int ct = 0; ct < 2; ct++) o[dt][ct] = (f32x4){0.f, 0.f, 0.f, 0.f};

  float mold[2] = {-1e30f, -1e30f};
  float lsum[2] = {0.f, 0.f};

  // prefetch j=0 tiles into registers
  uint4 gK[4], gV[4];
#pragma unroll
  for (int i = 0; i < 4; i++) {
    const int ch = i * 256 + tid;
    gK[i] = *(const uint4_a*)(Kh + (size_t)(ch >> 3) * DH + (ch & 7) * 8);
    gV[i] = *(const uint4_a*)(Vh + (size_t)(ch >> 4) * SEQ + (ch & 15) * 8);
  }

  for (int j = 0; j <= qt; j++) {
    __syncthreads();                     // prior Ks/VTs reads done
#pragma unroll
    for (int i = 0; i < 4; i++) {
      const int ch = i * 256 + tid;
      *(uint4_a*)&Ks[(ch >> 3) * 72 + (ch & 7) * 8]   = gK[i];
      *(uint4_a*)&VTs[(ch >> 4) * 136 + (ch & 15) * 8] = gV[i];
    }
    __syncthreads();                     // staging visible (no vm outstanding)

    if (j < qt) {                        // prefetch j+1; drains at P-barrier
      const int kb2 = (j + 1) * 128;
#pragma unroll
      for (int i = 0; i < 4; i++) {
        const int ch = i * 256 + tid;
        gK[i] = *(const uint4_a*)(Kh + (size_t)(kb2 + (ch >> 3)) * DH + (ch & 7) * 8);
        gV[i] = *(const uint4_a*)(Vh + (size_t)(ch >> 4) * SEQ + kb2 + (ch & 15) * 8);
      }
    }

    // S^T = K Q^T: rows kv (8x16), cols q (2x16/wave)
    f32x4 s[8][2];
#pragma unroll
    for (int rt = 0; rt < 8; rt++) {
      bf16x8 ka0 = *(const bf16x8_a*)&Ks[(rt * 16 + l16) * 72 + 0 + quad * 8];
      bf16x8 ka1 = *(const bf16x8_a*)&Ks[(rt * 16 + l16) * 72 + 32 + quad * 8];
#pragma unroll
      for (int ct = 0; ct < 2; ct++) {
        f32x4 c = (f32x4){0.f, 0.f, 0.f, 0.f};
        c = MFMA_BF16(ka0, qf[ct][0], c);
        c = MFMA_BF16(ka1, qf[ct][1], c);
        s[rt][ct] = c;
      }
    }

    if (j == qt) {                       // causal mask on diagonal tile
#pragma unroll
      for (int rt = 0; rt < 8; rt++)
#pragma unroll
        for (int ct = 0; ct < 2; ct++) {
          const int ql = wid * 32 + ct * 16 + l16;
#pragma unroll
          for (int r = 0; r < 4; r++) {
            const int kvl = rt * 16 + quad * 4 + r;
            if (kvl > ql) s[rt][ct][r] = -1e30f;
          }
        }
    }

    // online softmax per q col (state at l16, replicated across quads)
#pragma unroll
    for (int ct = 0; ct < 2; ct++) {
      float mt = -1e30f;
#pragma unroll
      for (int rt = 0; rt < 8; rt++)
#pragma unroll
        for (int r = 0; r < 4; r++) mt = fmaxf(mt, s[rt][ct][r]);
      mt = fmaxf(mt, __shfl_xor(mt, 16));
      mt = fmaxf(mt, __shfl_xor(mt, 32));
      const float mnew = fmaxf(mold[ct], mt);
      const float a = __builtin_amdgcn_exp2f((mold[ct] - mnew) * L2E);
      float ls = 0.f;
#pragma unroll
      for (int rt = 0; rt < 8; rt++)
#pragma unroll
        for (int r = 0; r < 4; r++) {
          const float p = __builtin_amdgcn_exp2f((s[rt][ct][r] - mnew) * L2E);
          s[rt][ct][r] = p;
          ls += p;
        }
      ls += __shfl_xor(ls, 16);
      ls += __shfl_xor(ls, 32);
      lsum[ct] = lsum[ct] * a + ls;
      mold[ct] = mnew;
#pragma unroll
      for (int dt = 0; dt < 4; dt++)
#pragma unroll
        for (int r = 0; r < 4; r++) o[dt][ct][r] *= a;
    }

    // P^T -> LDS: per (rt,ct) 4 consecutive kv pack to uint2 (16 writes)
    u16* Pw = &Ps[wid * 32 * 144];
#pragma unroll
    for (int rt = 0; rt < 8; rt++) {
#pragma unroll
      for (int ct = 0; ct < 2; ct++) {
        uint2 pk;
        pk.x = pack_bf2(s[rt][ct][0], s[rt][ct][1]);
        pk.y = pack_bf2(s[rt][ct][2], s[rt][ct][3]);
        *(uint2_a*)&Pw[(ct * 16 + l16) * 144 + rt * 16 + quad * 4] = pk;
      }
    }
    __syncthreads();                     // P visible; prefetch loads drained here

    // O^T += V^T P^T: A = VT rows (dh), B = P^T rows (q)
#pragma unroll
    for (int ks2 = 0; ks2 < 4; ks2++) {
      bf16x8 vt[4], pb[2];
#pragma unroll
      for (int dt = 0; dt < 4; dt++)
        vt[dt] = *(const bf16x8_a*)&VTs[(dt * 16 + l16) * 136 + ks2 * 32 + quad * 8];
#pragma unroll
      for (int ct = 0; ct < 2; ct++)
        pb[ct] = *(const bf16x8_a*)&Pw[(ct * 16 + l16) * 144 + ks2 * 32 + quad * 8];
#pragma unroll
      for (int dt = 0; dt < 4; dt++)
#pragma unroll
        for (int ct = 0; ct < 2; ct++)
          o[dt][ct] = MFMA_BF16(vt[dt], pb[ct], o[dt][ct]);
    }
  }

  // epilogue: O^T row dh = dt*16+quad*4+r, col q = l16 -> float4 stores
#pragma unroll
  for (int ct = 0; ct < 2; ct++) {
    const float inv = 1.0f / lsum[ct];
    const int qg = qbase + wid * 32 + ct * 16 + l16;
    float* orow = O + (size_t)((size_t)bb * SEQ + qg) * DMODEL + hh * 64;
#pragma unroll
    for (int dt = 0; dt < 4; dt++) {
      float4 v4;
      v4.x = o[dt][ct][0] * inv;  v4.y = o[dt][ct][1] * inv;
      v4.z = o[dt][ct][2] * inv;  v4.w = o[dt][ct][3] * inv;
      *(float4_a*)&orow[dt * 16 + quad * 4] = v4;
    }
  }
}

// Distinctive-paint sentinel (host-decided, graph-safe)
__global__ void paintf(float* out, int n, float v) {
  int i = blockIdx.x * 256 + threadIdx.x;
  if (i < n) out[i] = v;
}

extern "C" void kernel_launch(void* const* d_in, const int* in_sizes, int n_in,
                              void* d_out, int out_size, void* d_ws, size_t ws_size,
                              hipStream_t stream) {
  float* out = (float*)d_out;

  const size_t elems = (size_t)4 * SEQ * DMODEL;   // 8,388,608 per tensor
  if (ws_size < 3 * elems * sizeof(u16)) {
    paintf<<<(out_size + 255) / 256, 256, 0, stream>>>(out, out_size, 3.0e38f);
    return;
  }

  const float* x  = (const float*)d_in[0];
  // d_in[1] = mask (causal, unused — structure is known)
  const float* Wq = (const float*)d_in[2];
  const float* bq = (const float*)d_in[3];
  const float* Wk = (const float*)d_in[4];
  const float* bk = (const float*)d_in[5];
  const float* Wv = (const float*)d_in[6];
  const float* bv = (const float*)d_in[7];

  u16* q = (u16*)d_ws;
  u16* k = q + elems;
  u16* v = k + elems;   // holds V^T [B,H,DH,S]

  qkv_gemm<<<dim3(64, 8, 3), 256, 0, stream>>>(x, Wq, Wk, Wv, bq, bk, bv, q, k, v);
  flash_attn<<<1024, 256, 0, stream>>>(q, k, v, out);
}